// Round 6
// baseline (364.222 us; speedup 1.0000x reference)
//
#include <hip/hip_runtime.h>
#include <hip/hip_fp16.h>

// ---------------- constants ----------------
#define HIDW 64
#define EPSV 1e-5f
#define CAP 32        // bucket capacity per node; Poisson(16): ~15 edges overflow -> ovfl region 1
#define GRP 512       // nodes per owner group (k_own block); LDS buckets = GRP*CAP*4 = 64KB
#define CHUNK 4096    // edges per k_part block
#define PSLOTS 40     // slots per (bin,chunk) segment
#define NBIN_MAX 256
#define NCHUNK_MAX 512
#define NSLOT 64      // partial BN-stat slots
#define OVFR 32768    // per-region overflow capacity

// ---------------- init: zero deg / ovfcnt / stats ----------------
__global__ __launch_bounds__(256) void k_zero(int* __restrict__ deg, int* __restrict__ ovfcnt,
                                              float* __restrict__ stats, int n) {
    int i = blockIdx.x * 256 + threadIdx.x;
    if (i < n) deg[i] = 0;
    if (i < 2) ovfcnt[i] = 0;
    if (i < 3 * NSLOT * 128) stats[i] = 0.f;
}

// ---------------- P1: route 4096-edge chunks into static (bin = dst>>9) segments ----------------
__global__ __launch_bounds__(256) void k_part(const int* __restrict__ srcv, const int* __restrict__ dstv,
                                              int2* __restrict__ pairs, unsigned char* __restrict__ cnts,
                                              int2* __restrict__ ovfl, int* __restrict__ ovfcnt,
                                              int e, int nchunk, int nbin) {
    __shared__ int lcnt[NBIN_MAX];
    int tid = threadIdx.x;
    int chunk = blockIdx.x;
    for (int i = tid; i < nbin; i += 256) lcnt[i] = 0;
    __syncthreads();
    int base = chunk * CHUNK;
#pragma unroll
    for (int t = 0; t < CHUNK / 256; ++t) {
        int i = base + t * 256 + tid;
        if (i < e) {
            int s = srcv[i];
            int d = dstv[i];
            int k = d >> 9;
            int slot = atomicAdd(&lcnt[k], 1);
            if (slot < PSLOTS) {
                pairs[((size_t)k * nchunk + chunk) * PSLOTS + slot] = make_int2(s, d);
            } else {
                int o = atomicAdd(&ovfcnt[0], 1);
                if (o < OVFR) ovfl[o] = make_int2(s, d);
            }
        }
    }
    __syncthreads();
    for (int i = tid; i < nbin; i += 256)
        cnts[(size_t)i * nchunk + chunk] = (unsigned char)min(lcnt[i], PSLOTS);
}

// ---------------- P2: owner block per 512-node group; buckets built in LDS, flushed coalesced ----------------
__global__ __launch_bounds__(256) void k_own(const int2* __restrict__ pairs, const unsigned char* __restrict__ cnts,
                                             int* __restrict__ deg, unsigned char* __restrict__ bcnt,
                                             int* __restrict__ csr, int2* __restrict__ ovfl,
                                             int* __restrict__ ovfcnt, int n, int nchunk) {
    __shared__ int lcnt[GRP];
    __shared__ int bkt[GRP * CAP];           // 64 KB
    __shared__ unsigned char scnt[NCHUNK_MAX];
    int g = blockIdx.x;
    int tid = threadIdx.x;
    int nbase = g << 9;
    int nloc = min(GRP, n - nbase);
    for (int i = tid; i < GRP; i += 256) lcnt[i] = 0;
    for (int i = tid; i < nchunk; i += 256) scnt[i] = cnts[(size_t)g * nchunk + i];
    __syncthreads();
    const int2* pb = pairs + (size_t)g * nchunk * PSLOTS;
    int tot = nchunk * PSLOTS;
    for (int i = tid; i < tot; i += 256) {
        int c = i / PSLOTS;
        int s = i - c * PSLOTS;
        if (s < (int)scnt[c]) {
            int2 p = pb[i];
            int loc = p.y - nbase;
            int pos = atomicAdd(&lcnt[loc], 1);
            if (pos < CAP) {
                bkt[loc * CAP + pos] = p.x;
            } else {
                int o = atomicAdd(&ovfcnt[1], 1);
                if (o < OVFR) ovfl[OVFR + o] = p;
            }
        }
    }
    __syncthreads();
    int* csrb = csr + (size_t)nbase * CAP;
    for (int i = tid; i < nloc * CAP; i += 256) csrb[i] = bkt[i];
    for (int i = tid; i < nloc; i += 256) {
        int c = lcnt[i];
        deg[nbase + i] = c;                   // full count (incl. CAP-overflow edges)
        bcnt[nbase + i] = (unsigned char)min(c, CAP);
    }
}

// bin-overflow edges never reached k_own -> add them to deg before any dinv consumer
__global__ __launch_bounds__(256) void k_ovfdeg(const int2* __restrict__ ovfl, const int* __restrict__ ovfcnt,
                                                int* __restrict__ deg) {
    int m0 = min(ovfcnt[0], OVFR);
    for (int i = threadIdx.x; i < m0; i += 256) atomicAdd(&deg[ovfl[i].y], 1);
}

// overflow edges (~20): wave per edge, after gather. hw rows pre-scaled by dinv[src];
// weight = dinv[dst]. Absent from fused BN sums (mu shift ~5e-5, tolerated).
__global__ __launch_bounds__(256) void k_ovf(const __half* __restrict__ hw, const int2* __restrict__ ovfl,
                                             const int* __restrict__ ovfcnt, const int* __restrict__ deg,
                                             float* __restrict__ agg) {
    int m0 = min(ovfcnt[0], OVFR);
    int m1 = min(ovfcnt[1], OVFR);
    int tot = m0 + m1;
    if (tot == 0) return;
    int lane = threadIdx.x & 63;
    int w = (blockIdx.x * 256 + threadIdx.x) >> 6;
    for (; w < tot; w += gridDim.x * 4) {
        int2 p = (w < m0) ? ovfl[w] : ovfl[OVFR + (w - m0)];
        float wt = rsqrtf(1.0f + (float)deg[p.y]);
        atomicAdd(&agg[(size_t)p.y * HIDW + lane], __half2float(hw[(size_t)p.x * HIDW + lane]) * wt);
    }
}

// ---------------- path B (fallback, classic 2-pass CSR) ----------------
__global__ __launch_bounds__(256) void k_count(const int* __restrict__ dstv, int* __restrict__ deg, int e) {
    int i = blockIdx.x * 256 + threadIdx.x;
    if (i < e) atomicAdd(&deg[dstv[i]], 1);
}

__global__ __launch_bounds__(256) void k_scan1(const int* __restrict__ deg, int* __restrict__ off,
                                               int* __restrict__ bsum, int n) {
    __shared__ int s[256];
    int tid = threadIdx.x;
    int i = blockIdx.x * 256 + tid;
    int v = (i < n) ? deg[i] : 0;
    s[tid] = v;
    __syncthreads();
    for (int o = 1; o < 256; o <<= 1) {
        int t = (tid >= o) ? s[tid - o] : 0;
        __syncthreads();
        s[tid] += t;
        __syncthreads();
    }
    if (i < n) off[i] = s[tid] - v;
    if (tid == 255) bsum[blockIdx.x] = s[255];
}

__global__ __launch_bounds__(512) void k_scan2(int* __restrict__ bsum, int nb) {
    __shared__ int s[512];
    int tid = threadIdx.x;
    int v = (tid < nb) ? bsum[tid] : 0;
    s[tid] = v;
    __syncthreads();
    for (int o = 1; o < 512; o <<= 1) {
        int t = (tid >= o) ? s[tid - o] : 0;
        __syncthreads();
        s[tid] += t;
        __syncthreads();
    }
    if (tid < nb) bsum[tid] = s[tid] - v;
}

__global__ __launch_bounds__(256) void k_scan3(int* __restrict__ off, const int* __restrict__ bsum, int n) {
    int i = blockIdx.x * 256 + threadIdx.x;
    if (i < n) off[i] += bsum[blockIdx.x];
}

__global__ __launch_bounds__(256) void k_fill2(const int* __restrict__ srcv, const int* __restrict__ dstv,
                                               int* __restrict__ roff, int* __restrict__ csr, int e) {
    int i = blockIdx.x * 256 + threadIdx.x;
    if (i < e) {
        int d = dstv[i];
        int p = atomicAdd(&roff[d], 1);
        csr[p] = srcv[i];
    }
}

// ---------------- GEMM v2: hw[N,64] = dinv .* ( f(h)[N,K] @ W[K,64] ), fp16 out ----------------
// 256-node x 64-col tile, 8x8 register blocking (1 B LDS-read per FMA, was 2). x staged
// TRANSPOSED in K-chunks of 16 (sHT[16][260]: 16B-aligned rows, bank-spread); W row-major in
// LDS (broadcast reads). LDS: K=128 -> ~50KB (3 blk/CU), K=64 -> ~34KB (4 blk/CU); was 66.5KB
// (2 blk/CU, 16.5% occupancy, latency-bound).
template <int K, bool BN>
__global__ __launch_bounds__(256) void k_gemm(const float* __restrict__ h, const float* __restrict__ W,
                                              __half* __restrict__ hw, int n,
                                              const float* __restrict__ st, const float* __restrict__ g,
                                              const float* __restrict__ bt, float invn,
                                              const int* __restrict__ deg) {
    constexpr int KC = 16;
    constexpr int NCH = K / KC;
    constexpr int KQ = K / 4;
    constexpr int PT = 260;                 // sHT row pitch (floats): 16B-aligned, 4k+node banks
    __shared__ float sW[K * 64];
    __shared__ float sHT[KC][PT];
    __shared__ float sM[128];
    __shared__ float sSc[HIDW];
    __shared__ float sSh[HIDW];
    int tid = threadIdx.x;
    int tx = tid & 7;        // col-group: cols tx*8..+7
    int ty = tid >> 3;       // node-group: nodes ty*8..+7
    int node0 = blockIdx.x * 256;

    if (BN) {
        if (tid < 128) {
            float t = 0.f;
#pragma unroll 8
            for (int s = 0; s < NSLOT; ++s) t += st[s * 128 + tid];
            sM[tid] = t;
        }
        __syncthreads();
        if (tid < HIDW) {
            float mu = sM[tid] * invn;
            float var = sM[HIDW + tid] * invn - mu * mu;
            var = fmaxf(var, 0.f);
            float rstd = rsqrtf(var + EPSV);
            float sc = rstd * g[tid];
            sSc[tid] = sc;
            sSh[tid] = bt[tid] - mu * sc;
        }
    }

    for (int i = tid; i < K * 16; i += 256)
        ((float4*)sW)[i] = ((const float4*)W)[i];

    float acc[8][8];
#pragma unroll
    for (int j = 0; j < 8; ++j)
#pragma unroll
        for (int c = 0; c < 8; ++c) acc[j][c] = 0.f;

#pragma unroll 1
    for (int ch = 0; ch < NCH; ++ch) {
        int kc0 = ch * KC;
        __syncthreads();   // previous chunk fully consumed (also covers sW/BN staging on ch==0)
        // stage chunk transposed: 256 nodes x 16 K-vals = 1024 float4 / 256 thr = 4 each
#pragma unroll
        for (int it = 0; it < 4; ++it) {
            int i = it * 256 + tid;
            int node = i >> 2;
            int q = i & 3;                     // which float4 within the chunk
            int nn = node0 + node;
            if (nn >= n) nn = n - 1;
            float4 v = ((const float4*)h)[(size_t)nn * KQ + (kc0 >> 2) + q];
            if (BN) {
                int c = kc0 + 4 * q;
                v.x = fmaxf(fmaf(v.x, sSc[c + 0], sSh[c + 0]), 0.f);
                v.y = fmaxf(fmaf(v.y, sSc[c + 1], sSh[c + 1]), 0.f);
                v.z = fmaxf(fmaf(v.z, sSc[c + 2], sSh[c + 2]), 0.f);
                v.w = fmaxf(fmaf(v.w, sSc[c + 3], sSh[c + 3]), 0.f);
            }
            sHT[4 * q + 0][node] = v.x;
            sHT[4 * q + 1][node] = v.y;
            sHT[4 * q + 2][node] = v.z;
            sHT[4 * q + 3][node] = v.w;
        }
        __syncthreads();
#pragma unroll 4
        for (int kk = 0; kk < KC; ++kk) {
            float4 ha = *(const float4*)&sHT[kk][ty * 8];
            float4 hb = *(const float4*)&sHT[kk][ty * 8 + 4];
            const float* wr = sW + (kc0 + kk) * 64 + tx * 8;
            float4 wa = *(const float4*)wr;
            float4 wb = *(const float4*)(wr + 4);
            float hv[8] = {ha.x, ha.y, ha.z, ha.w, hb.x, hb.y, hb.z, hb.w};
            float wv[8] = {wa.x, wa.y, wa.z, wa.w, wb.x, wb.y, wb.z, wb.w};
#pragma unroll
            for (int j = 0; j < 8; ++j)
#pragma unroll
                for (int c = 0; c < 8; ++c)
                    acc[j][c] = fmaf(hv[j], wv[c], acc[j][c]);
        }
    }

#pragma unroll
    for (int j = 0; j < 8; ++j) {
        int node = node0 + ty * 8 + j;
        if (node < n) {
            float dv = rsqrtf(1.0f + (float)deg[node]);
            __half2 p0 = __floats2half2_rn(acc[j][0] * dv, acc[j][1] * dv);
            __half2 p1 = __floats2half2_rn(acc[j][2] * dv, acc[j][3] * dv);
            __half2 p2 = __floats2half2_rn(acc[j][4] * dv, acc[j][5] * dv);
            __half2 p3 = __floats2half2_rn(acc[j][6] * dv, acc[j][7] * dv);
            uint4 r;
            r.x = *(unsigned int*)&p0;
            r.y = *(unsigned int*)&p1;
            r.z = *(unsigned int*)&p2;
            r.w = *(unsigned int*)&p3;
            ((uint4*)hw)[(size_t)node * 8 + tx] = r;
        }
    }
}

// ---------------- gather v4 (bucket path): 8 nodes/wave + deep MLP ----------------
__global__ __launch_bounds__(256) void k_gath8(const __half* __restrict__ hw, const int* __restrict__ csr,
                                               const int* __restrict__ deg, const unsigned char* __restrict__ bcnt,
                                               const float* __restrict__ bias,
                                               float* __restrict__ agg, float* __restrict__ st, int n) {
    __shared__ float sS[4 * 64];
    __shared__ float sQ[4 * 64];
    int tid = threadIdx.x;
    int lane = tid & 63;
    int w = tid >> 6;
    int g = lane >> 3;   // node group 0..7
    int p = lane & 7;    // 16B column slice within the row
    int v = (blockIdx.x * 4 + w) * 8 + g;
    bool valid = (v < n);
    int vv = valid ? v : 0;
    int dcnt = deg[vv];
    int cnt = valid ? (int)bcnt[vv] : 0;
    float dv = rsqrtf(1.0f + (float)dcnt);
    const int* base = csr + (size_t)vv * CAP;
    const char* hwb = (const char*)hw;

    // whole bucket -> registers: lane p holds idx[4p..4p+3]
    uint4 iv = ((const uint4*)base)[p];

    float4 b0 = ((const float4*)bias)[p * 2 + 0];
    float4 b1 = ((const float4*)bias)[p * 2 + 1];

    float acc[8];
    {
        uint4 sv = make_uint4(0, 0, 0, 0);
        if (valid) sv = *(const uint4*)(hwb + (((unsigned)vv << 7) + (p << 4)));
        const __half2* hp = (const __half2*)&sv;
#pragma unroll
        for (int i = 0; i < 4; ++i) {
            float2 f = __half22float2(hp[i]);
            acc[2 * i + 0] = f.x;   // self-loop term (dv applied at end)
            acc[2 * i + 1] = f.y;
        }
    }

    // wave-max edge count (cnt uniform within each 8-lane group)
    int mc = cnt;
    mc = max(mc, __shfl_xor(mc, 8));
    mc = max(mc, __shfl_xor(mc, 16));
    mc = max(mc, __shfl_xor(mc, 32));

    int gl = lane & 56;  // g*8: first lane of this group
    for (int j0 = 0; j0 < mc; j0 += 8) {
        int sl = gl + (j0 >> 2);
        int idxs[8];
#pragma unroll
        for (int u = 0; u < 8; ++u) {
            int comp = u & 3;
            int word = (comp == 0) ? iv.x : (comp == 1) ? iv.y : (comp == 2) ? iv.z : iv.w;
            idxs[u] = __shfl(word, sl + (u >> 2));
        }
        uint4 rr[8];
#pragma unroll
        for (int u = 0; u < 8; ++u) {
            rr[u] = make_uint4(0, 0, 0, 0);
            if (j0 + u < cnt)
                rr[u] = *(const uint4*)(hwb + (((unsigned)idxs[u] << 7) + (p << 4)));
        }
#pragma unroll
        for (int u = 0; u < 8; ++u) {
            const __half2* hx = (const __half2*)&rr[u];
#pragma unroll
            for (int i = 0; i < 4; ++i) {
                float2 f = __half22float2(hx[i]);
                acc[2 * i + 0] += f.x;
                acc[2 * i + 1] += f.y;
            }
        }
    }

    float fin[8];
    fin[0] = fmaf(dv, acc[0], b0.x);
    fin[1] = fmaf(dv, acc[1], b0.y);
    fin[2] = fmaf(dv, acc[2], b0.z);
    fin[3] = fmaf(dv, acc[3], b0.w);
    fin[4] = fmaf(dv, acc[4], b1.x);
    fin[5] = fmaf(dv, acc[5], b1.y);
    fin[6] = fmaf(dv, acc[6], b1.z);
    fin[7] = fmaf(dv, acc[7], b1.w);
    if (valid) {
        float4 o0 = make_float4(fin[0], fin[1], fin[2], fin[3]);
        float4 o1 = make_float4(fin[4], fin[5], fin[6], fin[7]);
        float4* ap = (float4*)(agg + (size_t)vv * HIDW + p * 8);
        ap[0] = o0;
        ap[1] = o1;
    }
    float sv2[8], qv2[8];
#pragma unroll
    for (int i = 0; i < 8; ++i) {
        float t = valid ? fin[i] : 0.f;
        sv2[i] = t;
        qv2[i] = t * t;
    }
    // cross-group reduce (sum over the 8 nodes of this wave), once per wave
#pragma unroll
    for (int i = 0; i < 8; ++i) {
        sv2[i] += __shfl_xor(sv2[i], 8);
        qv2[i] += __shfl_xor(qv2[i], 8);
        sv2[i] += __shfl_xor(sv2[i], 16);
        qv2[i] += __shfl_xor(qv2[i], 16);
        sv2[i] += __shfl_xor(sv2[i], 32);
        qv2[i] += __shfl_xor(qv2[i], 32);
    }
    if (g == 0) {
#pragma unroll
        for (int i = 0; i < 8; ++i) {
            sS[w * 64 + p * 8 + i] = sv2[i];
            sQ[w * 64 + p * 8 + i] = qv2[i];
        }
    }
    __syncthreads();
    if (tid < 64) {
        float S = sS[tid] + sS[64 + tid] + sS[128 + tid] + sS[192 + tid];
        float Q = sQ[tid] + sQ[64 + tid] + sQ[128 + tid] + sQ[192 + tid];
        float* slot = st + (size_t)(blockIdx.x & (NSLOT - 1)) * 128;
        atomicAdd(&slot[tid], S);
        atomicAdd(&slot[64 + tid], Q);
    }
}

// ---------------- gather (path B fallback): wave per node, unbounded degree ----------------
__global__ __launch_bounds__(256) void k_gatherB(const __half* __restrict__ hw, const int* __restrict__ csr,
                                                 const int* __restrict__ roff, const int* __restrict__ deg,
                                                 const float* __restrict__ bias,
                                                 float* __restrict__ agg, float* __restrict__ st, int n) {
    __shared__ float sS[4 * 64];
    __shared__ float sQ[4 * 64];
    int tid = threadIdx.x;
    int lane = tid & 63;
    int w = tid >> 6;
    int eh = lane >> 3;
    int c8 = lane & 7;
    int v = blockIdx.x * 4 + w;
    bool valid = (v < n);
    int vv = valid ? v : 0;
    int dcnt = deg[vv];
    float dv = rsqrtf(1.0f + (float)dcnt);
    int cnt = dcnt;
    const int* base = csr + (roff[vv] - dcnt);
    const char* hwb = (const char*)hw;

    float acc[8];
    {
        unsigned off0 = ((unsigned)vv << 7) + (c8 << 4);
        uint4 sv = *(const uint4*)(hwb + off0);
        const __half2* hp = (const __half2*)&sv;
#pragma unroll
        for (int i = 0; i < 4; ++i) {
            float2 f = __half22float2(hp[i]);
            acc[2 * i + 0] = (eh == 0) ? f.x : 0.f;
            acc[2 * i + 1] = (eh == 0) ? f.y : 0.f;
        }
    }

    for (int j0 = 0; j0 < cnt; j0 += 64) {
        int m = min(cnt - j0, 64);
        int idx = (lane < m) ? base[j0 + lane] : 0;
        int k = 0;
        for (; k + 16 <= m; k += 16) {
            int a0 = __shfl(idx, k + eh);
            int a1 = __shfl(idx, k + 8 + eh);
            uint4 v0 = *(const uint4*)(hwb + (((unsigned)a0 << 7) + (c8 << 4)));
            uint4 v1 = *(const uint4*)(hwb + (((unsigned)a1 << 7) + (c8 << 4)));
            const __half2* h0 = (const __half2*)&v0;
            const __half2* h1 = (const __half2*)&v1;
#pragma unroll
            for (int i = 0; i < 4; ++i) {
                float2 f0 = __half22float2(h0[i]);
                float2 f1 = __half22float2(h1[i]);
                acc[2 * i + 0] += f0.x + f1.x;
                acc[2 * i + 1] += f0.y + f1.y;
            }
        }
        for (; k < m; k += 8) {
            int a = __shfl(idx, k + eh);
            uint4 v0 = *(const uint4*)(hwb + (((unsigned)a << 7) + (c8 << 4)));
            if (k + eh < m) {
                const __half2* h0 = (const __half2*)&v0;
#pragma unroll
                for (int i = 0; i < 4; ++i) {
                    float2 f0 = __half22float2(h0[i]);
                    acc[2 * i + 0] += f0.x;
                    acc[2 * i + 1] += f0.y;
                }
            }
        }
    }
#pragma unroll
    for (int i = 0; i < 8; ++i) {
        acc[i] += __shfl_xor(acc[i], 8);
        acc[i] += __shfl_xor(acc[i], 16);
        acc[i] += __shfl_xor(acc[i], 32);
    }
    if (eh == 0) {
        float4 b0 = ((const float4*)bias)[c8 * 2 + 0];
        float4 b1 = ((const float4*)bias)[c8 * 2 + 1];
        float4 f0, f1;
        f0.x = fmaf(dv, acc[0], b0.x);
        f0.y = fmaf(dv, acc[1], b0.y);
        f0.z = fmaf(dv, acc[2], b0.z);
        f0.w = fmaf(dv, acc[3], b0.w);
        f1.x = fmaf(dv, acc[4], b1.x);
        f1.y = fmaf(dv, acc[5], b1.y);
        f1.z = fmaf(dv, acc[6], b1.z);
        f1.w = fmaf(dv, acc[7], b1.w);
        if (valid) {
            ((float4*)agg)[(size_t)vv * 16 + c8 * 2 + 0] = f0;
            ((float4*)agg)[(size_t)vv * 16 + c8 * 2 + 1] = f1;
        }
        float s0[8] = {f0.x, f0.y, f0.z, f0.w, f1.x, f1.y, f1.z, f1.w};
#pragma unroll
        for (int i = 0; i < 8; ++i) {
            float sv2 = valid ? s0[i] : 0.f;
            sS[w * 64 + c8 * 8 + i] = sv2;
            sQ[w * 64 + c8 * 8 + i] = sv2 * sv2;
        }
    }
    __syncthreads();
    if (tid < 64) {
        float S = sS[tid] + sS[64 + tid] + sS[128 + tid] + sS[192 + tid];
        float Q = sQ[tid] + sQ[64 + tid] + sQ[128 + tid] + sQ[192 + tid];
        float* slot = st + (size_t)(blockIdx.x & (NSLOT - 1)) * 128;
        atomicAdd(&slot[tid], S);
        atomicAdd(&slot[64 + tid], Q);
    }
}

// ---------------- MLP head with layer-2 BN+ReLU folded in ----------------
__global__ __launch_bounds__(256) void k_head(const float* __restrict__ h, const float* __restrict__ lw1,
                                              const float* __restrict__ lb1, const float* __restrict__ lw2,
                                              const float* __restrict__ lb2, float* __restrict__ out, int n,
                                              const float* __restrict__ st, const float* __restrict__ g,
                                              const float* __restrict__ bt, float invn) {
    __shared__ float sW[64 * 32];
    __shared__ float sb1[32];
    __shared__ float sw2[32];
    __shared__ float sM[128];
    __shared__ float sSc[HIDW];
    __shared__ float sSh[HIDW];
    int tid = threadIdx.x;
    for (int i = tid; i < 64 * 32; i += 256) sW[i] = lw1[i];
    if (tid < 32) {
        sb1[tid] = lb1[tid];
        sw2[tid] = lw2[tid];
    }
    if (tid < 128) {
        float t = 0.f;
#pragma unroll 8
        for (int s = 0; s < NSLOT; ++s) t += st[s * 128 + tid];
        sM[tid] = t;
    }
    __syncthreads();
    if (tid < HIDW) {
        float mu = sM[tid] * invn;
        float var = sM[HIDW + tid] * invn - mu * mu;
        var = fmaxf(var, 0.f);
        float rstd = rsqrtf(var + EPSV);
        float sc = rstd * g[tid];
        sSc[tid] = sc;
        sSh[tid] = bt[tid] - mu * sc;
    }
    __syncthreads();
    int nd = blockIdx.x * 256 + tid;
    if (nd >= n) return;
    float acc[32];
#pragma unroll
    for (int j = 0; j < 32; ++j) acc[j] = sb1[j];
    const float4* hr = (const float4*)(h + (size_t)nd * HIDW);
#pragma unroll 4
    for (int kc = 0; kc < 16; ++kc) {
        float4 h4 = hr[kc];
        int c = 4 * kc;
        h4.x = fmaxf(fmaf(h4.x, sSc[c + 0], sSh[c + 0]), 0.f);
        h4.y = fmaxf(fmaf(h4.y, sSc[c + 1], sSh[c + 1]), 0.f);
        h4.z = fmaxf(fmaf(h4.z, sSc[c + 2], sSh[c + 2]), 0.f);
        h4.w = fmaxf(fmaf(h4.w, sSc[c + 3], sSh[c + 3]), 0.f);
        const float* w0 = &sW[(c + 0) * 32];
        const float* w1 = &sW[(c + 1) * 32];
        const float* w2 = &sW[(c + 2) * 32];
        const float* w3 = &sW[(c + 3) * 32];
#pragma unroll
        for (int j = 0; j < 32; ++j) {
            float t = fmaf(h4.x, w0[j], fmaf(h4.y, w1[j], fmaf(h4.z, w2[j], h4.w * w3[j])));
            acc[j] += t;
        }
    }
    float o = lb2[0];
#pragma unroll
    for (int j = 0; j < 32; ++j) o = fmaf(fmaxf(acc[j], 0.f), sw2[j], o);
    out[nd] = o;
}

// ---------------- launch ----------------
extern "C" void kernel_launch(void* const* d_in, const int* in_sizes, int n_in,
                              void* d_out, int out_size, void* d_ws, size_t ws_size,
                              hipStream_t stream) {
    const float* x = (const float*)d_in[0];
    const int* ei = (const int*)d_in[1];
    const float* W[3] = {(const float*)d_in[2], (const float*)d_in[6], (const float*)d_in[10]};
    const float* B[3] = {(const float*)d_in[3], (const float*)d_in[7], (const float*)d_in[11]};
    const float* G[3] = {(const float*)d_in[4], (const float*)d_in[8], (const float*)d_in[12]};
    const float* BT[3] = {(const float*)d_in[5], (const float*)d_in[9], (const float*)d_in[13]};
    const float* lw1 = (const float*)d_in[14];
    const float* lb1 = (const float*)d_in[15];
    const float* lw2 = (const float*)d_in[16];
    const float* lb2 = (const float*)d_in[17];
    float* out = (float*)d_out;

    const int n = in_sizes[0] / 128;  // 100000
    const int e = in_sizes[1] / 2;    // 1600000
    const int* srcv = ei;
    const int* dstv = ei + e;
    const float invn = 1.0f / (float)n;
    const int nchunk = (e + CHUNK - 1) / CHUNK;  // 391
    const int nbin = (n + GRP - 1) / GRP;        // 196

    char* ws = (char*)d_ws;
    size_t off = 0;
    auto alloc = [&](size_t bytes) -> char* {
        off = (off + 511) & ~(size_t)511;
        char* p = ws + off;
        off += bytes;
        return p;
    };
    float* stats = (float*)alloc((size_t)3 * NSLOT * 128 * 4);
    int* ovfcnt = (int*)alloc(512);
    int2* ovfl = (int2*)alloc((size_t)2 * OVFR * 8);
    unsigned char* cnts = (unsigned char*)alloc((size_t)nbin * nchunk);
    unsigned char* bcnt = (unsigned char*)alloc((size_t)n);
    int* deg = (int*)alloc((size_t)n * 4);
    float* bufA = (float*)alloc((size_t)n * HIDW * 4);   // agg; aliased as pairs during build
    __half* bufB = (__half*)alloc((size_t)n * HIDW * 2);
    size_t commonOff = off;

    // path A: csrB + pairs-alias fit check
    size_t needA = ((commonOff + 511) & ~(size_t)511) + (size_t)n * CAP * 4;
    size_t pairsBytes = (size_t)nbin * nchunk * PSLOTS * 8;
    bool useA = (needA <= ws_size) && (pairsBytes <= (size_t)n * HIDW * 4) &&
                (nchunk <= NCHUNK_MAX) && (nbin <= NBIN_MAX);

    const int gN = (n + 255) / 256;   // 391
    const int gG = (n + 255) / 256;   // 391 (256-node GEMM tiles)
    const int gV = (n + 3) / 4;       // 25000
    const int gV8 = (n + 31) / 32;    // 3125

    int2* pairs = (int2*)bufA;
    int* csrB = nullptr;
    int* roff = nullptr;
    int* bsum = nullptr;
    int* csrC = nullptr;

    if (useA) {
        csrB = (int*)alloc((size_t)n * CAP * 4);
        k_zero<<<gN, 256, 0, stream>>>(deg, ovfcnt, stats, n);
        k_part<<<nchunk, 256, 0, stream>>>(srcv, dstv, pairs, cnts, ovfl, ovfcnt, e, nchunk, nbin);
        k_own<<<nbin, 256, 0, stream>>>(pairs, cnts, deg, bcnt, csrB, ovfl, ovfcnt, n, nchunk);
        k_ovfdeg<<<1, 256, 0, stream>>>(ovfl, ovfcnt, deg);
    } else {
        roff = (int*)alloc((size_t)(n + 1) * 4);
        bsum = (int*)alloc(512 * 4);
        csrC = (int*)alloc((size_t)e * 4);
        k_zero<<<gN, 256, 0, stream>>>(deg, ovfcnt, stats, n);
        k_count<<<(e + 255) / 256, 256, 0, stream>>>(dstv, deg, e);
        k_scan1<<<gN, 256, 0, stream>>>(deg, roff, bsum, n);
        k_scan2<<<1, 512, 0, stream>>>(bsum, gN);
        k_scan3<<<gN, 256, 0, stream>>>(roff, bsum, n);
        k_fill2<<<(e + 255) / 256, 256, 0, stream>>>(srcv, dstv, roff, csrC, e);
    }

    for (int L = 0; L < 3; ++L) {
        float* stL = stats + (size_t)L * NSLOT * 128;
        if (L == 0)
            k_gemm<128, false><<<gG, 256, 0, stream>>>(x, W[0], bufB, n, nullptr, nullptr, nullptr, invn, deg);
        else
            k_gemm<64, true><<<gG, 256, 0, stream>>>(bufA, W[L], bufB, n, stats + (size_t)(L - 1) * NSLOT * 128,
                                                     G[L - 1], BT[L - 1], invn, deg);
        if (useA) {
            k_gath8<<<gV8, 256, 0, stream>>>(bufB, csrB, deg, bcnt, B[L], bufA, stL, n);
            k_ovf<<<16, 256, 0, stream>>>(bufB, ovfl, ovfcnt, deg, bufA);
        } else {
            k_gatherB<<<gV, 256, 0, stream>>>(bufB, csrC, roff, deg, B[L], bufA, stL, n);
        }
    }

    k_head<<<gN, 256, 0, stream>>>(bufA, lw1, lb1, lw2, lb2, out, n, stats + (size_t)2 * NSLOT * 128,
                                   G[2], BT[2], invn);
}

// Round 7
// 351.746 us; speedup vs baseline: 1.0355x; 1.0355x over previous
//
#include <hip/hip_runtime.h>
#include <hip/hip_fp16.h>

// ---------------- constants ----------------
#define HIDW 64
#define EPSV 1e-5f
#define CAP 32        // bucket capacity per node; Poisson(16): ~15 edges overflow -> ovfl region 1
#define GRP 512       // nodes per owner group (k_own block); LDS buckets = GRP*CAP*4 = 64KB
#define CHUNK 4096    // edges per k_part block
#define PSLOTS 40     // slots per (bin,chunk) segment
#define NBIN_MAX 256
#define NCHUNK_MAX 512
#define NSLOT 64      // partial BN-stat slots
#define OVFR 32768    // per-region overflow capacity

// ---------------- init: zero deg / ovfcnt / stats ----------------
__global__ __launch_bounds__(256) void k_zero(int* __restrict__ deg, int* __restrict__ ovfcnt,
                                              float* __restrict__ stats, int n) {
    int i = blockIdx.x * 256 + threadIdx.x;
    if (i < n) deg[i] = 0;
    if (i < 2) ovfcnt[i] = 0;
    if (i < 3 * NSLOT * 128) stats[i] = 0.f;
}

// ---------------- P1: route 4096-edge chunks into static (bin = dst>>9) segments ----------------
__global__ __launch_bounds__(256) void k_part(const int* __restrict__ srcv, const int* __restrict__ dstv,
                                              int2* __restrict__ pairs, unsigned char* __restrict__ cnts,
                                              int2* __restrict__ ovfl, int* __restrict__ ovfcnt,
                                              int e, int nchunk, int nbin) {
    __shared__ int lcnt[NBIN_MAX];
    int tid = threadIdx.x;
    int chunk = blockIdx.x;
    for (int i = tid; i < nbin; i += 256) lcnt[i] = 0;
    __syncthreads();
    int base = chunk * CHUNK;
#pragma unroll
    for (int t = 0; t < CHUNK / 256; ++t) {
        int i = base + t * 256 + tid;
        if (i < e) {
            int s = srcv[i];
            int d = dstv[i];
            int k = d >> 9;
            int slot = atomicAdd(&lcnt[k], 1);
            if (slot < PSLOTS) {
                pairs[((size_t)k * nchunk + chunk) * PSLOTS + slot] = make_int2(s, d);
            } else {
                int o = atomicAdd(&ovfcnt[0], 1);
                if (o < OVFR) ovfl[o] = make_int2(s, d);
            }
        }
    }
    __syncthreads();
    for (int i = tid; i < nbin; i += 256)
        cnts[(size_t)i * nchunk + chunk] = (unsigned char)min(lcnt[i], PSLOTS);
}

// ---------------- P2: owner block per 512-node group; buckets built in LDS, flushed coalesced ----------------
__global__ __launch_bounds__(256) void k_own(const int2* __restrict__ pairs, const unsigned char* __restrict__ cnts,
                                             int* __restrict__ deg, unsigned char* __restrict__ bcnt,
                                             int* __restrict__ csr, int2* __restrict__ ovfl,
                                             int* __restrict__ ovfcnt, int n, int nchunk) {
    __shared__ int lcnt[GRP];
    __shared__ int bkt[GRP * CAP];           // 64 KB
    __shared__ unsigned char scnt[NCHUNK_MAX];
    int g = blockIdx.x;
    int tid = threadIdx.x;
    int nbase = g << 9;
    int nloc = min(GRP, n - nbase);
    for (int i = tid; i < GRP; i += 256) lcnt[i] = 0;
    for (int i = tid; i < nchunk; i += 256) scnt[i] = cnts[(size_t)g * nchunk + i];
    __syncthreads();
    const int2* pb = pairs + (size_t)g * nchunk * PSLOTS;
    int tot = nchunk * PSLOTS;
    for (int i = tid; i < tot; i += 256) {
        int c = i / PSLOTS;
        int s = i - c * PSLOTS;
        if (s < (int)scnt[c]) {
            int2 p = pb[i];
            int loc = p.y - nbase;
            int pos = atomicAdd(&lcnt[loc], 1);
            if (pos < CAP) {
                bkt[loc * CAP + pos] = p.x;
            } else {
                int o = atomicAdd(&ovfcnt[1], 1);
                if (o < OVFR) ovfl[OVFR + o] = p;
            }
        }
    }
    __syncthreads();
    int* csrb = csr + (size_t)nbase * CAP;
    for (int i = tid; i < nloc * CAP; i += 256) csrb[i] = bkt[i];
    for (int i = tid; i < nloc; i += 256) {
        int c = lcnt[i];
        deg[nbase + i] = c;                   // full count (incl. CAP-overflow edges)
        bcnt[nbase + i] = (unsigned char)min(c, CAP);
    }
}

// bin-overflow edges never reached k_own -> add them to deg before any dinv consumer
__global__ __launch_bounds__(256) void k_ovfdeg(const int2* __restrict__ ovfl, const int* __restrict__ ovfcnt,
                                                int* __restrict__ deg) {
    int m0 = min(ovfcnt[0], OVFR);
    for (int i = threadIdx.x; i < m0; i += 256) atomicAdd(&deg[ovfl[i].y], 1);
}

// overflow edges (~20): wave per edge, after gather. hw rows pre-scaled by dinv[src];
// weight = dinv[dst]. Absent from fused BN sums (mu shift ~5e-5, tolerated).
__global__ __launch_bounds__(256) void k_ovf(const __half* __restrict__ hw, const int2* __restrict__ ovfl,
                                             const int* __restrict__ ovfcnt, const int* __restrict__ deg,
                                             float* __restrict__ agg) {
    int m0 = min(ovfcnt[0], OVFR);
    int m1 = min(ovfcnt[1], OVFR);
    int tot = m0 + m1;
    if (tot == 0) return;
    int lane = threadIdx.x & 63;
    int w = (blockIdx.x * 256 + threadIdx.x) >> 6;
    for (; w < tot; w += gridDim.x * 4) {
        int2 p = (w < m0) ? ovfl[w] : ovfl[OVFR + (w - m0)];
        float wt = rsqrtf(1.0f + (float)deg[p.y]);
        atomicAdd(&agg[(size_t)p.y * HIDW + lane], __half2float(hw[(size_t)p.x * HIDW + lane]) * wt);
    }
}

// ---------------- path B (fallback, classic 2-pass CSR) ----------------
__global__ __launch_bounds__(256) void k_count(const int* __restrict__ dstv, int* __restrict__ deg, int e) {
    int i = blockIdx.x * 256 + threadIdx.x;
    if (i < e) atomicAdd(&deg[dstv[i]], 1);
}

__global__ __launch_bounds__(256) void k_scan1(const int* __restrict__ deg, int* __restrict__ off,
                                               int* __restrict__ bsum, int n) {
    __shared__ int s[256];
    int tid = threadIdx.x;
    int i = blockIdx.x * 256 + tid;
    int v = (i < n) ? deg[i] : 0;
    s[tid] = v;
    __syncthreads();
    for (int o = 1; o < 256; o <<= 1) {
        int t = (tid >= o) ? s[tid - o] : 0;
        __syncthreads();
        s[tid] += t;
        __syncthreads();
    }
    if (i < n) off[i] = s[tid] - v;
    if (tid == 255) bsum[blockIdx.x] = s[255];
}

__global__ __launch_bounds__(512) void k_scan2(int* __restrict__ bsum, int nb) {
    __shared__ int s[512];
    int tid = threadIdx.x;
    int v = (tid < nb) ? bsum[tid] : 0;
    s[tid] = v;
    __syncthreads();
    for (int o = 1; o < 512; o <<= 1) {
        int t = (tid >= o) ? s[tid - o] : 0;
        __syncthreads();
        s[tid] += t;
        __syncthreads();
    }
    if (tid < nb) bsum[tid] = s[tid] - v;
}

__global__ __launch_bounds__(256) void k_scan3(int* __restrict__ off, const int* __restrict__ bsum, int n) {
    int i = blockIdx.x * 256 + threadIdx.x;
    if (i < n) off[i] += bsum[blockIdx.x];
}

__global__ __launch_bounds__(256) void k_fill2(const int* __restrict__ srcv, const int* __restrict__ dstv,
                                               int* __restrict__ roff, int* __restrict__ csr, int e) {
    int i = blockIdx.x * 256 + threadIdx.x;
    if (i < e) {
        int d = dstv[i];
        int p = atomicAdd(&roff[d], 1);
        csr[p] = srcv[i];
    }
}

// ---------------- GEMM v3: hw[N,64] = dinv .* ( f(h)[N,K] @ W[K,64] ), fp16 out ----------------
// 128-node x 64-col tile (782 blocks -> ~3 blocks/CU, 12 waves/CU; v2's 391-block grid left
// half the CUs at 1 block = 11% occupancy). 4x8 register tile (1.5 B LDS-read/FMA). x staged
// transposed per 16-K chunk (sHT[16][132]); W row-major (broadcast). LDS: K=128 ~41KB, K=64 ~25KB.
template <int K, bool BN>
__global__ __launch_bounds__(256) void k_gemm(const float* __restrict__ h, const float* __restrict__ W,
                                              __half* __restrict__ hw, int n,
                                              const float* __restrict__ st, const float* __restrict__ g,
                                              const float* __restrict__ bt, float invn,
                                              const int* __restrict__ deg) {
    constexpr int KC = 16;
    constexpr int NCH = K / KC;
    constexpr int KQ = K / 4;
    constexpr int PT = 132;                 // sHT row pitch (floats): 16B-aligned, bank-spread
    __shared__ float sW[K * 64];
    __shared__ float sHT[KC][PT];
    __shared__ float sM[128];
    __shared__ float sSc[HIDW];
    __shared__ float sSh[HIDW];
    int tid = threadIdx.x;
    int tx = tid & 7;        // col-group: cols tx*8..+7
    int ty = tid >> 3;       // node-group: nodes ty*4..+3
    int node0 = blockIdx.x * 128;

    if (BN) {
        if (tid < 128) {
            float t = 0.f;
#pragma unroll 8
            for (int s = 0; s < NSLOT; ++s) t += st[s * 128 + tid];
            sM[tid] = t;
        }
        __syncthreads();
        if (tid < HIDW) {
            float mu = sM[tid] * invn;
            float var = sM[HIDW + tid] * invn - mu * mu;
            var = fmaxf(var, 0.f);
            float rstd = rsqrtf(var + EPSV);
            float sc = rstd * g[tid];
            sSc[tid] = sc;
            sSh[tid] = bt[tid] - mu * sc;
        }
    }

    for (int i = tid; i < K * 16; i += 256)
        ((float4*)sW)[i] = ((const float4*)W)[i];

    float acc[4][8];
#pragma unroll
    for (int j = 0; j < 4; ++j)
#pragma unroll
        for (int c = 0; c < 8; ++c) acc[j][c] = 0.f;

#pragma unroll 1
    for (int ch = 0; ch < NCH; ++ch) {
        int kc0 = ch * KC;
        __syncthreads();   // previous chunk fully consumed (also covers sW/BN staging on ch==0)
        // stage chunk transposed: 128 nodes x 16 K-vals = 512 float4 / 256 thr = 2 each
#pragma unroll
        for (int it = 0; it < 2; ++it) {
            int i = it * 256 + tid;
            int node = i >> 2;
            int q = i & 3;                     // which float4 within the chunk
            int nn = node0 + node;
            if (nn >= n) nn = n - 1;
            float4 v = ((const float4*)h)[(size_t)nn * KQ + (kc0 >> 2) + q];
            if (BN) {
                int c = kc0 + 4 * q;
                v.x = fmaxf(fmaf(v.x, sSc[c + 0], sSh[c + 0]), 0.f);
                v.y = fmaxf(fmaf(v.y, sSc[c + 1], sSh[c + 1]), 0.f);
                v.z = fmaxf(fmaf(v.z, sSc[c + 2], sSh[c + 2]), 0.f);
                v.w = fmaxf(fmaf(v.w, sSc[c + 3], sSh[c + 3]), 0.f);
            }
            sHT[4 * q + 0][node] = v.x;
            sHT[4 * q + 1][node] = v.y;
            sHT[4 * q + 2][node] = v.z;
            sHT[4 * q + 3][node] = v.w;
        }
        __syncthreads();
#pragma unroll 4
        for (int kk = 0; kk < KC; ++kk) {
            float4 ha = *(const float4*)&sHT[kk][ty * 4];
            const float* wr = sW + (kc0 + kk) * 64 + tx * 8;
            float4 wa = *(const float4*)wr;
            float4 wb = *(const float4*)(wr + 4);
            float hv[4] = {ha.x, ha.y, ha.z, ha.w};
            float wv[8] = {wa.x, wa.y, wa.z, wa.w, wb.x, wb.y, wb.z, wb.w};
#pragma unroll
            for (int j = 0; j < 4; ++j)
#pragma unroll
                for (int c = 0; c < 8; ++c)
                    acc[j][c] = fmaf(hv[j], wv[c], acc[j][c]);
        }
    }

#pragma unroll
    for (int j = 0; j < 4; ++j) {
        int node = node0 + ty * 4 + j;
        if (node < n) {
            float dv = rsqrtf(1.0f + (float)deg[node]);
            __half2 p0 = __floats2half2_rn(acc[j][0] * dv, acc[j][1] * dv);
            __half2 p1 = __floats2half2_rn(acc[j][2] * dv, acc[j][3] * dv);
            __half2 p2 = __floats2half2_rn(acc[j][4] * dv, acc[j][5] * dv);
            __half2 p3 = __floats2half2_rn(acc[j][6] * dv, acc[j][7] * dv);
            uint4 r;
            r.x = *(unsigned int*)&p0;
            r.y = *(unsigned int*)&p1;
            r.z = *(unsigned int*)&p2;
            r.w = *(unsigned int*)&p3;
            ((uint4*)hw)[(size_t)node * 8 + tx] = r;
        }
    }
}

// ---------------- gather v4 (bucket path): 8 nodes/wave + deep MLP ----------------
__global__ __launch_bounds__(256) void k_gath8(const __half* __restrict__ hw, const int* __restrict__ csr,
                                               const int* __restrict__ deg, const unsigned char* __restrict__ bcnt,
                                               const float* __restrict__ bias,
                                               float* __restrict__ agg, float* __restrict__ st, int n) {
    __shared__ float sS[4 * 64];
    __shared__ float sQ[4 * 64];
    int tid = threadIdx.x;
    int lane = tid & 63;
    int w = tid >> 6;
    int g = lane >> 3;   // node group 0..7
    int p = lane & 7;    // 16B column slice within the row
    int v = (blockIdx.x * 4 + w) * 8 + g;
    bool valid = (v < n);
    int vv = valid ? v : 0;
    int dcnt = deg[vv];
    int cnt = valid ? (int)bcnt[vv] : 0;
    float dv = rsqrtf(1.0f + (float)dcnt);
    const int* base = csr + (size_t)vv * CAP;
    const char* hwb = (const char*)hw;

    // whole bucket -> registers: lane p holds idx[4p..4p+3]
    uint4 iv = ((const uint4*)base)[p];

    float4 b0 = ((const float4*)bias)[p * 2 + 0];
    float4 b1 = ((const float4*)bias)[p * 2 + 1];

    float acc[8];
    {
        uint4 sv = make_uint4(0, 0, 0, 0);
        if (valid) sv = *(const uint4*)(hwb + (((unsigned)vv << 7) + (p << 4)));
        const __half2* hp = (const __half2*)&sv;
#pragma unroll
        for (int i = 0; i < 4; ++i) {
            float2 f = __half22float2(hp[i]);
            acc[2 * i + 0] = f.x;   // self-loop term (dv applied at end)
            acc[2 * i + 1] = f.y;
        }
    }

    // wave-max edge count (cnt uniform within each 8-lane group)
    int mc = cnt;
    mc = max(mc, __shfl_xor(mc, 8));
    mc = max(mc, __shfl_xor(mc, 16));
    mc = max(mc, __shfl_xor(mc, 32));

    int gl = lane & 56;  // g*8: first lane of this group
    for (int j0 = 0; j0 < mc; j0 += 8) {
        int sl = gl + (j0 >> 2);
        int idxs[8];
#pragma unroll
        for (int u = 0; u < 8; ++u) {
            int comp = u & 3;
            int word = (comp == 0) ? iv.x : (comp == 1) ? iv.y : (comp == 2) ? iv.z : iv.w;
            idxs[u] = __shfl(word, sl + (u >> 2));
        }
        uint4 rr[8];
#pragma unroll
        for (int u = 0; u < 8; ++u) {
            rr[u] = make_uint4(0, 0, 0, 0);
            if (j0 + u < cnt)
                rr[u] = *(const uint4*)(hwb + (((unsigned)idxs[u] << 7) + (p << 4)));
        }
#pragma unroll
        for (int u = 0; u < 8; ++u) {
            const __half2* hx = (const __half2*)&rr[u];
#pragma unroll
            for (int i = 0; i < 4; ++i) {
                float2 f = __half22float2(hx[i]);
                acc[2 * i + 0] += f.x;
                acc[2 * i + 1] += f.y;
            }
        }
    }

    float fin[8];
    fin[0] = fmaf(dv, acc[0], b0.x);
    fin[1] = fmaf(dv, acc[1], b0.y);
    fin[2] = fmaf(dv, acc[2], b0.z);
    fin[3] = fmaf(dv, acc[3], b0.w);
    fin[4] = fmaf(dv, acc[4], b1.x);
    fin[5] = fmaf(dv, acc[5], b1.y);
    fin[6] = fmaf(dv, acc[6], b1.z);
    fin[7] = fmaf(dv, acc[7], b1.w);
    if (valid) {
        float4 o0 = make_float4(fin[0], fin[1], fin[2], fin[3]);
        float4 o1 = make_float4(fin[4], fin[5], fin[6], fin[7]);
        float4* ap = (float4*)(agg + (size_t)vv * HIDW + p * 8);
        ap[0] = o0;
        ap[1] = o1;
    }
    float sv2[8], qv2[8];
#pragma unroll
    for (int i = 0; i < 8; ++i) {
        float t = valid ? fin[i] : 0.f;
        sv2[i] = t;
        qv2[i] = t * t;
    }
    // cross-group reduce (sum over the 8 nodes of this wave), once per wave
#pragma unroll
    for (int i = 0; i < 8; ++i) {
        sv2[i] += __shfl_xor(sv2[i], 8);
        qv2[i] += __shfl_xor(qv2[i], 8);
        sv2[i] += __shfl_xor(sv2[i], 16);
        qv2[i] += __shfl_xor(qv2[i], 16);
        sv2[i] += __shfl_xor(sv2[i], 32);
        qv2[i] += __shfl_xor(qv2[i], 32);
    }
    if (g == 0) {
#pragma unroll
        for (int i = 0; i < 8; ++i) {
            sS[w * 64 + p * 8 + i] = sv2[i];
            sQ[w * 64 + p * 8 + i] = qv2[i];
        }
    }
    __syncthreads();
    if (tid < 64) {
        float S = sS[tid] + sS[64 + tid] + sS[128 + tid] + sS[192 + tid];
        float Q = sQ[tid] + sQ[64 + tid] + sQ[128 + tid] + sQ[192 + tid];
        float* slot = st + (size_t)(blockIdx.x & (NSLOT - 1)) * 128;
        atomicAdd(&slot[tid], S);
        atomicAdd(&slot[64 + tid], Q);
    }
}

// ---------------- gather (path B fallback): wave per node, unbounded degree ----------------
__global__ __launch_bounds__(256) void k_gatherB(const __half* __restrict__ hw, const int* __restrict__ csr,
                                                 const int* __restrict__ roff, const int* __restrict__ deg,
                                                 const float* __restrict__ bias,
                                                 float* __restrict__ agg, float* __restrict__ st, int n) {
    __shared__ float sS[4 * 64];
    __shared__ float sQ[4 * 64];
    int tid = threadIdx.x;
    int lane = tid & 63;
    int w = tid >> 6;
    int eh = lane >> 3;
    int c8 = lane & 7;
    int v = blockIdx.x * 4 + w;
    bool valid = (v < n);
    int vv = valid ? v : 0;
    int dcnt = deg[vv];
    float dv = rsqrtf(1.0f + (float)dcnt);
    int cnt = dcnt;
    const int* base = csr + (roff[vv] - dcnt);
    const char* hwb = (const char*)hw;

    float acc[8];
    {
        unsigned off0 = ((unsigned)vv << 7) + (c8 << 4);
        uint4 sv = *(const uint4*)(hwb + off0);
        const __half2* hp = (const __half2*)&sv;
#pragma unroll
        for (int i = 0; i < 4; ++i) {
            float2 f = __half22float2(hp[i]);
            acc[2 * i + 0] = (eh == 0) ? f.x : 0.f;
            acc[2 * i + 1] = (eh == 0) ? f.y : 0.f;
        }
    }

    for (int j0 = 0; j0 < cnt; j0 += 64) {
        int m = min(cnt - j0, 64);
        int idx = (lane < m) ? base[j0 + lane] : 0;
        int k = 0;
        for (; k + 16 <= m; k += 16) {
            int a0 = __shfl(idx, k + eh);
            int a1 = __shfl(idx, k + 8 + eh);
            uint4 v0 = *(const uint4*)(hwb + (((unsigned)a0 << 7) + (c8 << 4)));
            uint4 v1 = *(const uint4*)(hwb + (((unsigned)a1 << 7) + (c8 << 4)));
            const __half2* h0 = (const __half2*)&v0;
            const __half2* h1 = (const __half2*)&v1;
#pragma unroll
            for (int i = 0; i < 4; ++i) {
                float2 f0 = __half22float2(h0[i]);
                float2 f1 = __half22float2(h1[i]);
                acc[2 * i + 0] += f0.x + f1.x;
                acc[2 * i + 1] += f0.y + f1.y;
            }
        }
        for (; k < m; k += 8) {
            int a = __shfl(idx, k + eh);
            uint4 v0 = *(const uint4*)(hwb + (((unsigned)a << 7) + (c8 << 4)));
            if (k + eh < m) {
                const __half2* h0 = (const __half2*)&v0;
#pragma unroll
                for (int i = 0; i < 4; ++i) {
                    float2 f0 = __half22float2(h0[i]);
                    acc[2 * i + 0] += f0.x;
                    acc[2 * i + 1] += f0.y;
                }
            }
        }
    }
#pragma unroll
    for (int i = 0; i < 8; ++i) {
        acc[i] += __shfl_xor(acc[i], 8);
        acc[i] += __shfl_xor(acc[i], 16);
        acc[i] += __shfl_xor(acc[i], 32);
    }
    if (eh == 0) {
        float4 b0 = ((const float4*)bias)[c8 * 2 + 0];
        float4 b1 = ((const float4*)bias)[c8 * 2 + 1];
        float4 f0, f1;
        f0.x = fmaf(dv, acc[0], b0.x);
        f0.y = fmaf(dv, acc[1], b0.y);
        f0.z = fmaf(dv, acc[2], b0.z);
        f0.w = fmaf(dv, acc[3], b0.w);
        f1.x = fmaf(dv, acc[4], b1.x);
        f1.y = fmaf(dv, acc[5], b1.y);
        f1.z = fmaf(dv, acc[6], b1.z);
        f1.w = fmaf(dv, acc[7], b1.w);
        if (valid) {
            ((float4*)agg)[(size_t)vv * 16 + c8 * 2 + 0] = f0;
            ((float4*)agg)[(size_t)vv * 16 + c8 * 2 + 1] = f1;
        }
        float s0[8] = {f0.x, f0.y, f0.z, f0.w, f1.x, f1.y, f1.z, f1.w};
#pragma unroll
        for (int i = 0; i < 8; ++i) {
            float sv2 = valid ? s0[i] : 0.f;
            sS[w * 64 + c8 * 8 + i] = sv2;
            sQ[w * 64 + c8 * 8 + i] = sv2 * sv2;
        }
    }
    __syncthreads();
    if (tid < 64) {
        float S = sS[tid] + sS[64 + tid] + sS[128 + tid] + sS[192 + tid];
        float Q = sQ[tid] + sQ[64 + tid] + sQ[128 + tid] + sQ[192 + tid];
        float* slot = st + (size_t)(blockIdx.x & (NSLOT - 1)) * 128;
        atomicAdd(&slot[tid], S);
        atomicAdd(&slot[64 + tid], Q);
    }
}

// ---------------- MLP head with layer-2 BN+ReLU folded in ----------------
__global__ __launch_bounds__(256) void k_head(const float* __restrict__ h, const float* __restrict__ lw1,
                                              const float* __restrict__ lb1, const float* __restrict__ lw2,
                                              const float* __restrict__ lb2, float* __restrict__ out, int n,
                                              const float* __restrict__ st, const float* __restrict__ g,
                                              const float* __restrict__ bt, float invn) {
    __shared__ float sW[64 * 32];
    __shared__ float sb1[32];
    __shared__ float sw2[32];
    __shared__ float sM[128];
    __shared__ float sSc[HIDW];
    __shared__ float sSh[HIDW];
    int tid = threadIdx.x;
    for (int i = tid; i < 64 * 32; i += 256) sW[i] = lw1[i];
    if (tid < 32) {
        sb1[tid] = lb1[tid];
        sw2[tid] = lw2[tid];
    }
    if (tid < 128) {
        float t = 0.f;
#pragma unroll 8
        for (int s = 0; s < NSLOT; ++s) t += st[s * 128 + tid];
        sM[tid] = t;
    }
    __syncthreads();
    if (tid < HIDW) {
        float mu = sM[tid] * invn;
        float var = sM[HIDW + tid] * invn - mu * mu;
        var = fmaxf(var, 0.f);
        float rstd = rsqrtf(var + EPSV);
        float sc = rstd * g[tid];
        sSc[tid] = sc;
        sSh[tid] = bt[tid] - mu * sc;
    }
    __syncthreads();
    int nd = blockIdx.x * 256 + tid;
    if (nd >= n) return;
    float acc[32];
#pragma unroll
    for (int j = 0; j < 32; ++j) acc[j] = sb1[j];
    const float4* hr = (const float4*)(h + (size_t)nd * HIDW);
#pragma unroll 4
    for (int kc = 0; kc < 16; ++kc) {
        float4 h4 = hr[kc];
        int c = 4 * kc;
        h4.x = fmaxf(fmaf(h4.x, sSc[c + 0], sSh[c + 0]), 0.f);
        h4.y = fmaxf(fmaf(h4.y, sSc[c + 1], sSh[c + 1]), 0.f);
        h4.z = fmaxf(fmaf(h4.z, sSc[c + 2], sSh[c + 2]), 0.f);
        h4.w = fmaxf(fmaf(h4.w, sSc[c + 3], sSh[c + 3]), 0.f);
        const float* w0 = &sW[(c + 0) * 32];
        const float* w1 = &sW[(c + 1) * 32];
        const float* w2 = &sW[(c + 2) * 32];
        const float* w3 = &sW[(c + 3) * 32];
#pragma unroll
        for (int j = 0; j < 32; ++j) {
            float t = fmaf(h4.x, w0[j], fmaf(h4.y, w1[j], fmaf(h4.z, w2[j], h4.w * w3[j])));
            acc[j] += t;
        }
    }
    float o = lb2[0];
#pragma unroll
    for (int j = 0; j < 32; ++j) o = fmaf(fmaxf(acc[j], 0.f), sw2[j], o);
    out[nd] = o;
}

// ---------------- launch ----------------
extern "C" void kernel_launch(void* const* d_in, const int* in_sizes, int n_in,
                              void* d_out, int out_size, void* d_ws, size_t ws_size,
                              hipStream_t stream) {
    const float* x = (const float*)d_in[0];
    const int* ei = (const int*)d_in[1];
    const float* W[3] = {(const float*)d_in[2], (const float*)d_in[6], (const float*)d_in[10]};
    const float* B[3] = {(const float*)d_in[3], (const float*)d_in[7], (const float*)d_in[11]};
    const float* G[3] = {(const float*)d_in[4], (const float*)d_in[8], (const float*)d_in[12]};
    const float* BT[3] = {(const float*)d_in[5], (const float*)d_in[9], (const float*)d_in[13]};
    const float* lw1 = (const float*)d_in[14];
    const float* lb1 = (const float*)d_in[15];
    const float* lw2 = (const float*)d_in[16];
    const float* lb2 = (const float*)d_in[17];
    float* out = (float*)d_out;

    const int n = in_sizes[0] / 128;  // 100000
    const int e = in_sizes[1] / 2;    // 1600000
    const int* srcv = ei;
    const int* dstv = ei + e;
    const float invn = 1.0f / (float)n;
    const int nchunk = (e + CHUNK - 1) / CHUNK;  // 391
    const int nbin = (n + GRP - 1) / GRP;        // 196

    char* ws = (char*)d_ws;
    size_t off = 0;
    auto alloc = [&](size_t bytes) -> char* {
        off = (off + 511) & ~(size_t)511;
        char* p = ws + off;
        off += bytes;
        return p;
    };
    float* stats = (float*)alloc((size_t)3 * NSLOT * 128 * 4);
    int* ovfcnt = (int*)alloc(512);
    int2* ovfl = (int2*)alloc((size_t)2 * OVFR * 8);
    unsigned char* cnts = (unsigned char*)alloc((size_t)nbin * nchunk);
    unsigned char* bcnt = (unsigned char*)alloc((size_t)n);
    int* deg = (int*)alloc((size_t)n * 4);
    float* bufA = (float*)alloc((size_t)n * HIDW * 4);   // agg; aliased as pairs during build
    __half* bufB = (__half*)alloc((size_t)n * HIDW * 2);
    size_t commonOff = off;

    // path A: csrB + pairs-alias fit check
    size_t needA = ((commonOff + 511) & ~(size_t)511) + (size_t)n * CAP * 4;
    size_t pairsBytes = (size_t)nbin * nchunk * PSLOTS * 8;
    bool useA = (needA <= ws_size) && (pairsBytes <= (size_t)n * HIDW * 4) &&
                (nchunk <= NCHUNK_MAX) && (nbin <= NBIN_MAX);

    const int gN = (n + 255) / 256;   // 391
    const int gG = (n + 127) / 128;   // 782 (128-node GEMM tiles)
    const int gV = (n + 3) / 4;       // 25000
    const int gV8 = (n + 31) / 32;    // 3125

    int2* pairs = (int2*)bufA;
    int* csrB = nullptr;
    int* roff = nullptr;
    int* bsum = nullptr;
    int* csrC = nullptr;

    if (useA) {
        csrB = (int*)alloc((size_t)n * CAP * 4);
        k_zero<<<gN, 256, 0, stream>>>(deg, ovfcnt, stats, n);
        k_part<<<nchunk, 256, 0, stream>>>(srcv, dstv, pairs, cnts, ovfl, ovfcnt, e, nchunk, nbin);
        k_own<<<nbin, 256, 0, stream>>>(pairs, cnts, deg, bcnt, csrB, ovfl, ovfcnt, n, nchunk);
        k_ovfdeg<<<1, 256, 0, stream>>>(ovfl, ovfcnt, deg);
    } else {
        roff = (int*)alloc((size_t)(n + 1) * 4);
        bsum = (int*)alloc(512 * 4);
        csrC = (int*)alloc((size_t)e * 4);
        k_zero<<<gN, 256, 0, stream>>>(deg, ovfcnt, stats, n);
        k_count<<<(e + 255) / 256, 256, 0, stream>>>(dstv, deg, e);
        k_scan1<<<gN, 256, 0, stream>>>(deg, roff, bsum, n);
        k_scan2<<<1, 512, 0, stream>>>(bsum, gN);
        k_scan3<<<gN, 256, 0, stream>>>(roff, bsum, n);
        k_fill2<<<(e + 255) / 256, 256, 0, stream>>>(srcv, dstv, roff, csrC, e);
    }

    for (int L = 0; L < 3; ++L) {
        float* stL = stats + (size_t)L * NSLOT * 128;
        if (L == 0)
            k_gemm<128, false><<<gG, 256, 0, stream>>>(x, W[0], bufB, n, nullptr, nullptr, nullptr, invn, deg);
        else
            k_gemm<64, true><<<gG, 256, 0, stream>>>(bufA, W[L], bufB, n, stats + (size_t)(L - 1) * NSLOT * 128,
                                                     G[L - 1], BT[L - 1], invn, deg);
        if (useA) {
            k_gath8<<<gV8, 256, 0, stream>>>(bufB, csrB, deg, bcnt, B[L], bufA, stL, n);
            k_ovf<<<16, 256, 0, stream>>>(bufB, ovfl, ovfcnt, deg, bufA);
        } else {
            k_gatherB<<<gV, 256, 0, stream>>>(bufB, csrC, roff, deg, B[L], bufA, stL, n);
        }
    }

    k_head<<<gN, 256, 0, stream>>>(bufA, lw1, lb1, lw2, lb2, out, n, stats + (size_t)2 * NSLOT * 128,
                                   G[2], BT[2], invn);
}